// Round 11
// baseline (321.670 us; speedup 1.0000x reference)
//
#include <hip/hip_runtime.h>
#include <hip/hip_bf16.h>
#include <hip/hip_cooperative_groups.h>

namespace cg = cooperative_groups;

// Problem constants
#define B_  2
#define S_  2048
#define E_  512
#define H_  8
#define D_  64
#define BS_ (B_ * S_)   // 4096 rows
#define N1_ 1536        // fused tri-projection output cols
#define K_  512

typedef __bf16 bf16x8 __attribute__((ext_vector_type(8)));
typedef float  f32x4  __attribute__((ext_vector_type(4)));
typedef unsigned short us8 __attribute__((ext_vector_type(8)));

// float -> bf16 (RNE) bit trick
__device__ __forceinline__ ushort f2bf(float f) {
    unsigned u = __float_as_uint(f);
    unsigned r = (u + 0x7FFFu + ((u >> 16) & 1u)) >> 16;
    return (ushort)r;
}
__device__ __forceinline__ float bf2f(ushort b) {
    return __uint_as_float(((unsigned)b) << 16);
}

// async global->LDS, 16 B per lane; LDS dest = wave-uniform base + lane*16
__device__ __forceinline__ void gld_lds16(const ushort* g, ushort* l) {
    __builtin_amdgcn_global_load_lds(
        (const __attribute__((address_space(1))) unsigned int*)g,
        (__attribute__((address_space(3))) unsigned int*)l, 16, 0, 0);
}

// ============ single cooperative kernel: prep -> GEMM1 -> attn -> GEMM2 ======
// 512 blocks x 256 threads, __launch_bounds__(256,2) -> 2 blocks/CU co-resident
// (LDS 28 KB/block, fits 2/CU trivially). Phases separated by grid.sync().
// Each phase body is the round-8 kernel (best measured: 114.7 us) verbatim.
__global__ __launch_bounds__(256, 2) void fused_kernel(
    const float* __restrict__ x, const int* __restrict__ parent,
    const float* __restrict__ Wp, const float* __restrict__ bp,
    const float* __restrict__ Wc, const float* __restrict__ bc,
    const float* __restrict__ Ws, const float* __restrict__ bs,
    const float* __restrict__ Wo, const float* __restrict__ bo,
    float* __restrict__ out,
    ushort* __restrict__ x_bf, ushort* __restrict__ Wcat_t,
    ushort* __restrict__ Wo_t, ushort* __restrict__ PCS,
    ushort* __restrict__ attn) {
    __shared__ ushort smem[14336];   // 28 KB, aliased per phase
    cg::grid_group grid = cg::this_grid();

    const int bx   = blockIdx.x;
    const int tid  = threadIdx.x;
    const int lane = tid & 63;
    const int wave = tid >> 6;

    // ---------------- Phase 0: prep (convert x, transpose weights) ----------
    {
        int gtid = bx * 256 + tid;               // 131072 threads
        #pragma unroll
        for (int t = 0; t < 4; t++) {            // 524288 float4s of x
            int idx = t * 131072 + gtid;
            float4 v = ((const float4*)x)[idx];
            ushort4 o;
            o.x = f2bf(v.x); o.y = f2bf(v.y); o.z = f2bf(v.z); o.w = f2bf(v.w);
            ((ushort4*)x_bf)[idx] = o;
        }
        if (bx < 256) {                          // 4 matrices x 64 tiles
            ushort (*T)[65] = (ushort(*)[65])smem;
            int z = bx >> 6, t = bx & 63;
            const float* src = (z == 0) ? Wp : (z == 1) ? Wc : (z == 2) ? Ws : Wo;
            ushort* dst = (z < 3) ? (Wcat_t + (size_t)z * 512 * 512) : Wo_t;
            int n0 = (t & 7) * 64, k0 = (t >> 3) * 64;
            int g = tid >> 6, l = tid & 63;
            #pragma unroll
            for (int r = 0; r < 16; r++) {
                int kk = g * 16 + r;
                T[kk][l] = f2bf(src[(size_t)(k0 + kk) * 512 + n0 + l]);
            }
            __syncthreads();
            #pragma unroll
            for (int r = 0; r < 16; r++) {
                int nn = g * 16 + r;
                dst[(size_t)(n0 + nn) * 512 + k0 + l] = T[l][nn];
            }
        }
    }
    grid.sync();

    // ---------------- Phase 1: GEMM1  PCS = x @ [Wp|Wc|Ws] + bias -----------
    // 128x96 tile; 512 blocks = 16 col-tiles x 32 row-tiles; async staging.
    {
        ushort (*As)[64] = (ushort(*)[64])smem;          // 128 rows, 16 KB
        ushort (*Bs)[64] = (ushort(*)[64])(smem + 8192); //  96 rows, 12 KB
        const int wm = wave >> 1, wn = wave & 1;
        const int row0 = (bx >> 4) * 128;
        const int col0 = (bx & 15) * 96;
        f32x4 acc[4][3] = {};
        const int srow = lane >> 3;
        const int scol = (lane & 7) * 8;
        const int lrow = lane & 15;
        const int lk   = (lane >> 4) * 8;

        for (int kt = 0; kt < K_; kt += 64) {
            const ushort* ga = x_bf + (size_t)(row0 + wave * 32 + srow) * K_ + kt + scol;
            #pragma unroll
            for (int j = 0; j < 4; j++)
                gld_lds16(ga + (size_t)j * 8 * K_, &As[wave * 32 + j * 8][0]);
            const ushort* gb = Wcat_t + (size_t)(col0 + wave * 24 + srow) * K_ + kt + scol;
            #pragma unroll
            for (int j = 0; j < 3; j++)
                gld_lds16(gb + (size_t)j * 8 * K_, &Bs[wave * 24 + j * 8][0]);
            __syncthreads();

            #pragma unroll
            for (int kk = 0; kk < 64; kk += 32) {
                bf16x8 af[4], bfr[3];
                #pragma unroll
                for (int i = 0; i < 4; i++)
                    af[i] = *(const bf16x8*)(&As[wm * 64 + i * 16 + lrow][kk + lk]);
                #pragma unroll
                for (int j = 0; j < 3; j++)
                    bfr[j] = *(const bf16x8*)(&Bs[wn * 48 + j * 16 + lrow][kk + lk]);
                #pragma unroll
                for (int i = 0; i < 4; i++)
                    #pragma unroll
                    for (int j = 0; j < 3; j++)
                        acc[i][j] = __builtin_amdgcn_mfma_f32_16x16x32_bf16(
                            af[i], bfr[j], acc[i][j], 0, 0, 0);
            }
            __syncthreads();
        }

        // C/D layout: col = lane&15, row = (lane>>4)*4 + reg [m89/m91 verified]
        const int ccol = lane & 15;
        const int crow = (lane >> 4) * 4;
        #pragma unroll
        for (int j = 0; j < 3; j++) {
            int gcol = col0 + wn * 48 + j * 16 + ccol;
            float bias = (gcol < 512) ? bp[gcol]
                       : (gcol < 1024) ? bc[gcol - 512] : bs[gcol - 1024];
            #pragma unroll
            for (int i = 0; i < 4; i++) {
                int grow = row0 + wm * 64 + i * 16 + crow;
                #pragma unroll
                for (int rg = 0; rg < 4; rg++)
                    PCS[(size_t)(grow + rg) * N1_ + gcol] = f2bf(acc[i][j][rg] + bias);
            }
        }
    }
    grid.sync();

    // ---------------- Phase 2: tree attention (2 rows per wave) -------------
    // PCS row (1536 bf16): [p|c|s]; lane L owns 8 elems at offset L*8/segment
    // (head h=L>>3). Neighbor set {parent[n]} ∪ {m:parent[m]==n} \ dups,
    // fixed scan order -> bit-deterministic. NOTE: alpha is PER-HEAD — the
    // s@Wo pre-fold is invalid (round-7 post-mortem).
    {
        int wid = bx * 4 + wave;                 // 0..2047
        for (int r = 0; r < 2; r++) {
            int w = wid * 2 + r;                 // 0..4095
            int bbase = ((w >> 11) << 11);
            int i  = w & (S_ - 1);
            int rp = bbase + parent[w];

            float pnf[8];
            {
                us8 p8 = *(const us8*)(PCS + (size_t)w * N1_ + lane * 8);
                #pragma unroll
                for (int j = 0; j < 8; j++) pnf[j] = bf2f(p8[j]);
            }

            float Z, av[8];
            {
                const ushort* rm = PCS + (size_t)rp * N1_;
                us8 c8 = *(const us8*)(rm + 512  + lane * 8);
                us8 s8 = *(const us8*)(rm + 1024 + lane * 8);
                float t = 0.f;
                #pragma unroll
                for (int j = 0; j < 8; j++) t += pnf[j] * bf2f(c8[j]);
                t += __shfl_xor(t, 1); t += __shfl_xor(t, 2); t += __shfl_xor(t, 4);
                float e = __expf(t * 0.125f);    // 1/sqrt(D) = 1/8
                Z = e;
                #pragma unroll
                for (int j = 0; j < 8; j++) av[j] = e * bf2f(s8[j]);
            }

            for (int t0 = 0; t0 < S_; t0 += 256) {
                int4 pv = *(const int4*)(parent + bbase + t0 + lane * 4);
                int pc[4] = {pv.x, pv.y, pv.z, pv.w};
                #pragma unroll
                for (int jj = 0; jj < 4; jj++) {
                    unsigned long long mask = __ballot(pc[jj] == i);
                    while (mask) {
                        int l = __ffsll(mask) - 1;
                        mask &= mask - 1;
                        int c = bbase + t0 + l * 4 + jj;
                        if (c == rp) continue;   // mutual/self edge counted once
                        const ushort* rc = PCS + (size_t)c * N1_;
                        us8 c8 = *(const us8*)(rc + 512  + lane * 8);
                        us8 s8 = *(const us8*)(rc + 1024 + lane * 8);
                        float t = 0.f;
                        #pragma unroll
                        for (int j = 0; j < 8; j++) t += pnf[j] * bf2f(c8[j]);
                        t += __shfl_xor(t, 1); t += __shfl_xor(t, 2); t += __shfl_xor(t, 4);
                        float e = __expf(t * 0.125f);
                        Z += e;
                        #pragma unroll
                        for (int j = 0; j < 8; j++) av[j] += e * bf2f(s8[j]);
                    }
                }
            }

            float rz = 1.0f / Z;
            us8 o8;
            #pragma unroll
            for (int j = 0; j < 8; j++) o8[j] = f2bf(av[j] * rz);
            *(us8*)(attn + (size_t)w * E_ + lane * 8) = o8;
        }
    }
    grid.sync();

    // ---------------- Phase 3: GEMM2  out = attn @ Wo + bo ------------------
    // 64x64 tile; 512 blocks = 8 col-tiles x 64 row-tiles; both operands bf16
    // async staged (Wo_t from phase 0).
    {
        ushort (*As2)[64] = (ushort(*)[64])smem;           // 64 rows, 8 KB
        ushort (*Bs2)[64] = (ushort(*)[64])(smem + 4096);  // 64 rows, 8 KB
        const int wm = wave >> 1, wn = wave & 1;
        const int row0 = (bx >> 3) * 64;
        const int col0 = (bx & 7) * 64;
        f32x4 acc[2][2] = {};
        const int srow = lane >> 3;
        const int scol = (lane & 7) * 8;
        const int lrow = lane & 15;
        const int lk   = (lane >> 4) * 8;

        for (int kt = 0; kt < K_; kt += 64) {
            const ushort* ga = attn + (size_t)(row0 + wave * 16 + srow) * K_ + kt + scol;
            gld_lds16(ga,           &As2[wave * 16 + 0][0]);
            gld_lds16(ga + 8 * K_,  &As2[wave * 16 + 8][0]);
            const ushort* gb = Wo_t + (size_t)(col0 + wave * 16 + srow) * K_ + kt + scol;
            gld_lds16(gb,           &Bs2[wave * 16 + 0][0]);
            gld_lds16(gb + 8 * K_,  &Bs2[wave * 16 + 8][0]);
            __syncthreads();

            #pragma unroll
            for (int kk = 0; kk < 64; kk += 32) {
                bf16x8 af[2], bfr[2];
                #pragma unroll
                for (int i = 0; i < 2; i++)
                    af[i] = *(const bf16x8*)(&As2[wm * 32 + i * 16 + lrow][kk + lk]);
                #pragma unroll
                for (int j = 0; j < 2; j++)
                    bfr[j] = *(const bf16x8*)(&Bs2[wn * 32 + j * 16 + lrow][kk + lk]);
                #pragma unroll
                for (int i = 0; i < 2; i++)
                    #pragma unroll
                    for (int j = 0; j < 2; j++)
                        acc[i][j] = __builtin_amdgcn_mfma_f32_16x16x32_bf16(
                            af[i], bfr[j], acc[i][j], 0, 0, 0);
            }
            __syncthreads();
        }

        const int ccol = lane & 15;
        const int crow = (lane >> 4) * 4;
        #pragma unroll
        for (int j = 0; j < 2; j++) {
            int gcol = col0 + wn * 32 + j * 16 + ccol;
            float bias = bo[gcol];
            #pragma unroll
            for (int i = 0; i < 2; i++) {
                int grow = row0 + wm * 32 + i * 16 + crow;
                #pragma unroll
                for (int rg = 0; rg < 4; rg++)
                    out[(size_t)(grow + rg) * E_ + gcol] = acc[i][j][rg] + bias;
            }
        }
    }
}

// ---------------- launch ----------------
extern "C" void kernel_launch(void* const* d_in, const int* in_sizes, int n_in,
                              void* d_out, int out_size, void* d_ws, size_t ws_size,
                              hipStream_t stream) {
    const float* x      = (const float*)d_in[0];
    const int*   parent = (const int*)  d_in[1];
    const float* Wp     = (const float*)d_in[2];
    const float* bp     = (const float*)d_in[3];
    const float* Wc     = (const float*)d_in[4];
    const float* bc     = (const float*)d_in[5];
    const float* Ws     = (const float*)d_in[6];
    const float* bs     = (const float*)d_in[7];
    const float* Wo     = (const float*)d_in[8];
    const float* bo     = (const float*)d_in[9];
    float* out = (float*)d_out;

    char* ws = (char*)d_ws;
    // workspace layout; every byte read is written earlier in the same call
    ushort* x_bf    = (ushort*)(ws + 0);          //  4,194,304
    ushort* Wcat_t  = (ushort*)(ws + 4194304);    //  1,572,864
    ushort* Wo_t    = (ushort*)(ws + 5767168);    //    524,288
    ushort* PCS_bf  = (ushort*)(ws + 6291456);    // 12,582,912
    ushort* attn_bf = (ushort*)(ws + 18874368);   //  4,194,304  (end ~23.1 MB)

    void* args[] = {
        (void*)&x, (void*)&parent,
        (void*)&Wp, (void*)&bp, (void*)&Wc, (void*)&bc,
        (void*)&Ws, (void*)&bs, (void*)&Wo, (void*)&bo,
        (void*)&out,
        (void*)&x_bf, (void*)&Wcat_t, (void*)&Wo_t,
        (void*)&PCS_bf, (void*)&attn_bf,
    };
    hipLaunchCooperativeKernel((void*)fused_kernel, dim3(512), dim3(256),
                               args, 0, stream);
}

// Round 12
// 116.578 us; speedup vs baseline: 2.7593x; 2.7593x over previous
//
#include <hip/hip_runtime.h>
#include <hip/hip_bf16.h>

// Problem constants
#define B_  2
#define S_  2048
#define E_  512
#define H_  8
#define D_  64
#define BS_ (B_ * S_)   // 4096 rows
#define N1_ 1536        // fused tri-projection output cols
#define K_  512

typedef __bf16 bf16x8 __attribute__((ext_vector_type(8)));
typedef float  f32x4  __attribute__((ext_vector_type(4)));
typedef unsigned short us8 __attribute__((ext_vector_type(8)));

// float -> bf16 (RNE) bit trick
__device__ __forceinline__ ushort f2bf(float f) {
    unsigned u = __float_as_uint(f);
    unsigned r = (u + 0x7FFFu + ((u >> 16) & 1u)) >> 16;
    return (ushort)r;
}
__device__ __forceinline__ float bf2f(ushort b) {
    return __uint_as_float(((unsigned)b) << 16);
}

// async global->LDS, 16 B per lane; LDS dest = wave-uniform base + lane*16
__device__ __forceinline__ void gld_lds16(const ushort* g, ushort* l) {
    __builtin_amdgcn_global_load_lds(
        (const __attribute__((address_space(1))) unsigned int*)g,
        (__attribute__((address_space(3))) unsigned int*)l, 16, 0, 0);
}

// ---------------- merged prep kernel ----------------
// blocks [0,2048): fp32->bf16 convert of x (one float4 per thread)
// blocks [2048,2304): 64x64 transpose tiles of the four 512x512 weights
__global__ __launch_bounds__(256) void prep_kernel(
    const float* __restrict__ x, ushort* __restrict__ xb,
    const float* __restrict__ Wp, const float* __restrict__ Wc,
    const float* __restrict__ Ws, const float* __restrict__ Wo,
    ushort* __restrict__ Wcat_t, ushort* __restrict__ Wo_t) {
    int bid = blockIdx.x;
    int tid = threadIdx.x;
    if (bid < 2048) {
        int i = bid * 256 + tid;          // 524288 float4s total
        float4 v = ((const float4*)x)[i];
        ushort4 o;
        o.x = f2bf(v.x); o.y = f2bf(v.y); o.z = f2bf(v.z); o.w = f2bf(v.w);
        ((ushort4*)xb)[i] = o;
        return;
    }
    __shared__ ushort T[64][65];
    int bid2 = bid - 2048;                // 0..255
    int z = bid2 >> 6;
    int t = bid2 & 63;
    const float* src = (z == 0) ? Wp : (z == 1) ? Wc : (z == 2) ? Ws : Wo;
    ushort* dst = (z < 3) ? (Wcat_t + (size_t)z * 512 * 512) : Wo_t;
    int n0 = (t & 7) * 64, k0 = (t >> 3) * 64;
    int g = tid >> 6, l = tid & 63;
    #pragma unroll
    for (int r = 0; r < 16; r++) {
        int kk = g * 16 + r;
        T[kk][l] = f2bf(src[(size_t)(k0 + kk) * 512 + n0 + l]);  // coalesced read
    }
    __syncthreads();
    #pragma unroll
    for (int r = 0; r < 16; r++) {
        int nn = g * 16 + r;
        dst[(size_t)(n0 + nn) * 512 + k0 + l] = T[l][nn];        // coalesced write
    }
}

// ---------------- bf16 MFMA GEMM (m97 structure, tile+TK templated) ----------
// C[M x N] = A[M x K](bf16) * Bt[N x K](bf16)^T + bias; output fp32 or bf16.
// 256 threads = 4 waves in 2x2; per-wave FM x NF fragments of 16x16x32.
// TK=128 halves the per-K-loop barrier drains vs TK=64 (same staging bytes).
template<int TM, int TN, int TK, bool BF16OUT>
__global__ __launch_bounds__(256) void gemm_mfma_kernel(
    const ushort* __restrict__ A,   // M x K
    const ushort* __restrict__ Bt,  // N x K
    const float*  __restrict__ b0,  // bias cols [0,512)
    const float*  __restrict__ b1,  // bias cols [512,1024)
    const float*  __restrict__ b2,  // bias cols [1024,1536)
    void* __restrict__ Cv,          // M x N
    int N, int K) {
    constexpr int FM  = TM / 32;         // m-frags per wave
    constexpr int NF  = TN / 32;         // n-frags per wave
    constexpr int RPI = 512 / TK;        // LDS rows filled per 1KB wave issue
    constexpr int LPR = TK / 8;          // lanes per LDS row during staging
    __shared__ ushort As[TM][TK];        // no pad (global_load_lds layout)
    __shared__ ushort Bs[TN][TK];

    const int tid  = threadIdx.x;
    const int lane = tid & 63;
    const int wave = tid >> 6;
    const int wm = wave >> 1, wn = wave & 1;
    const int row0 = blockIdx.y * TM;
    const int col0 = blockIdx.x * TN;

    f32x4 acc[FM][NF] = {};

    const int srow = lane / LPR;         // staging row within an issue
    const int scol = (lane % LPR) * 8;   // 8-bf16 chunk

    const int lrow = lane & 15;
    const int lk   = (lane >> 4) * 8;

    for (int kt = 0; kt < K; kt += TK) {
        const ushort* ga = A + (size_t)(row0 + wave * (TM / 4) + srow) * K + kt + scol;
        #pragma unroll
        for (int j = 0; j < (TM / 4) / RPI; j++)
            gld_lds16(ga + (size_t)j * RPI * K, &As[wave * (TM / 4) + j * RPI][0]);
        const ushort* gb = Bt + (size_t)(col0 + wave * (TN / 4) + srow) * K + kt + scol;
        #pragma unroll
        for (int j = 0; j < (TN / 4) / RPI; j++)
            gld_lds16(gb + (size_t)j * RPI * K, &Bs[wave * (TN / 4) + j * RPI][0]);
        __syncthreads();

        #pragma unroll
        for (int kk = 0; kk < TK; kk += 32) {
            bf16x8 af[FM], bfr[NF];
            #pragma unroll
            for (int i = 0; i < FM; i++)
                af[i] = *(const bf16x8*)(&As[wm * (FM * 16) + i * 16 + lrow][kk + lk]);
            #pragma unroll
            for (int j = 0; j < NF; j++)
                bfr[j] = *(const bf16x8*)(&Bs[wn * (TN / 2) + j * 16 + lrow][kk + lk]);
            #pragma unroll
            for (int i = 0; i < FM; i++)
                #pragma unroll
                for (int j = 0; j < NF; j++)
                    acc[i][j] = __builtin_amdgcn_mfma_f32_16x16x32_bf16(
                        af[i], bfr[j], acc[i][j], 0, 0, 0);
        }
        __syncthreads();
    }

    // C/D layout: col = lane&15, row = (lane>>4)*4 + reg  [m89/m91 verified]
    const int ccol = lane & 15;
    const int crow = (lane >> 4) * 4;
    #pragma unroll
    for (int j = 0; j < NF; j++) {
        int gcol = col0 + wn * (TN / 2) + j * 16 + ccol;
        float bias = (gcol < 512) ? b0[gcol]
                   : (gcol < 1024) ? b1[gcol - 512] : b2[gcol - 1024];
        #pragma unroll
        for (int i = 0; i < FM; i++) {
            int grow = row0 + wm * (FM * 16) + i * 16 + crow;
            #pragma unroll
            for (int rg = 0; rg < 4; rg++) {
                float v = acc[i][j][rg] + bias;
                if (BF16OUT)
                    ((ushort*)Cv)[(size_t)(grow + rg) * N + gcol] = f2bf(v);
                else
                    ((float*)Cv)[(size_t)(grow + rg) * N + gcol] = v;
            }
        }
    }
}

// ---------------- tree attention: 16B/lane ballot-scan gather ----------------
// PCS (bf16) row layout per token w (1536): [p(512)|c(512)|s(512)], each h*64+d.
// One wave per row n. Lane L owns 8 consecutive elements at offset L*8 of each
// 512-segment: head h = L>>3. Per edge: two dwordx4 loads, 8-FMA dot partial,
// shfl_xor(1,2,4) head-group reduce, one exp, 8 FMAs. Neighbor set
// {parent[n]} ∪ {m:parent[m]==n} minus duplicates, fixed order -> deterministic.
// NOTE: alpha is PER-HEAD — the s@Wo pre-fold is invalid (round-7 post-mortem).
// NOTE: grid-wide sync via cooperative launch costs ~60us/sync on gfx950
// (round-11 post-mortem) — keep phases as separate graph nodes.
__global__ __launch_bounds__(256) void attn_gather_kernel(
    const ushort* __restrict__ PCS, const int* __restrict__ parent,
    ushort* __restrict__ attn) {
    int gtid = blockIdx.x * blockDim.x + threadIdx.x;
    int w    = gtid >> 6;        // token row 0..BS_-1
    int lane = gtid & 63;
    int bbase = ((w >> 11) << 11);
    int i  = w & (S_ - 1);
    int rp = bbase + parent[w];

    // p fragment: 8 consecutive bf16 at w*1536 + lane*8
    float pnf[8];
    {
        us8 p8 = *(const us8*)(PCS + (size_t)w * N1_ + lane * 8);
        #pragma unroll
        for (int j = 0; j < 8; j++) pnf[j] = bf2f(p8[j]);
    }

    float Z, av[8];
    // parent edge (always present in the mask)
    {
        const ushort* rm = PCS + (size_t)rp * N1_;
        us8 c8 = *(const us8*)(rm + 512  + lane * 8);
        us8 s8 = *(const us8*)(rm + 1024 + lane * 8);
        float t = 0.f;
        #pragma unroll
        for (int j = 0; j < 8; j++) t += pnf[j] * bf2f(c8[j]);
        t += __shfl_xor(t, 1); t += __shfl_xor(t, 2); t += __shfl_xor(t, 4);
        float e = __expf(t * 0.125f);          // 1/sqrt(D) = 1/8
        Z = e;
        #pragma unroll
        for (int j = 0; j < 8; j++) av[j] = e * bf2f(s8[j]);
    }

    // children: scan this batch's parent slice, 256 ints per step (int4/lane)
    for (int t0 = 0; t0 < S_; t0 += 256) {
        int4 pv = *(const int4*)(parent + bbase + t0 + lane * 4);
        int pc[4] = {pv.x, pv.y, pv.z, pv.w};
        #pragma unroll
        for (int jj = 0; jj < 4; jj++) {
            unsigned long long mask = __ballot(pc[jj] == i);
            while (mask) {
                int l = __ffsll(mask) - 1;
                mask &= mask - 1;
                int c = bbase + t0 + l * 4 + jj;
                if (c == rp) continue;         // mutual/self edge counted once
                const ushort* rc = PCS + (size_t)c * N1_;
                us8 c8 = *(const us8*)(rc + 512  + lane * 8);
                us8 s8 = *(const us8*)(rc + 1024 + lane * 8);
                float t = 0.f;
                #pragma unroll
                for (int j = 0; j < 8; j++) t += pnf[j] * bf2f(c8[j]);
                t += __shfl_xor(t, 1); t += __shfl_xor(t, 2); t += __shfl_xor(t, 4);
                float e = __expf(t * 0.125f);
                Z += e;
                #pragma unroll
                for (int j = 0; j < 8; j++) av[j] += e * bf2f(s8[j]);
            }
        }
    }

    float rz = 1.0f / Z;
    us8 o8;
    #pragma unroll
    for (int j = 0; j < 8; j++) o8[j] = f2bf(av[j] * rz);
    *(us8*)(attn + (size_t)w * E_ + lane * 8) = o8;
}

// ---------------- launch ----------------
extern "C" void kernel_launch(void* const* d_in, const int* in_sizes, int n_in,
                              void* d_out, int out_size, void* d_ws, size_t ws_size,
                              hipStream_t stream) {
    const float* x      = (const float*)d_in[0];
    const int*   parent = (const int*)  d_in[1];
    const float* Wp     = (const float*)d_in[2];
    const float* bp     = (const float*)d_in[3];
    const float* Wc     = (const float*)d_in[4];
    const float* bc     = (const float*)d_in[5];
    const float* Ws     = (const float*)d_in[6];
    const float* bs     = (const float*)d_in[7];
    const float* Wo     = (const float*)d_in[8];
    const float* bo     = (const float*)d_in[9];
    float* out = (float*)d_out;

    char* ws = (char*)d_ws;
    // workspace layout (bytes, 256-aligned); every byte read is written first
    ushort* x_bf    = (ushort*)(ws + 0);          //  4,194,304
    ushort* Wcat_t  = (ushort*)(ws + 4194304);    //  1,572,864
    ushort* Wo_t    = (ushort*)(ws + 5767168);    //    524,288
    ushort* PCS_bf  = (ushort*)(ws + 6291456);    // 12,582,912
    ushort* attn_bf = (ushort*)(ws + 18874368);   //  4,194,304  (end ~23.1 MB)

    // prep: convert x (2048 blocks) + transpose weights (256 blocks)
    prep_kernel<<<2304, 256, 0, stream>>>(x, x_bf, Wp, Wc, Ws, Wo, Wcat_t, Wo_t);

    // GEMM1: PCS(bf16) = x @ [Wp|Wc|Ws] + [bp|bc|bs]
    // 128x96 tile, BK=128 (4 K-iterations, half the barrier drains);
    // 16x32 = 512 blocks = exactly 2.0 blocks/CU (56 KB LDS -> 2/CU by LDS too)
    gemm_mfma_kernel<128, 96, 128, true>
        <<<dim3(N1_ / 96, BS_ / 128), 256, 0, stream>>>(
        x_bf, Wcat_t, bp, bc, bs, PCS_bf, N1_, K_);

    // tree attention: deterministic gather, 16B/lane loads, no atomics
    attn_gather_kernel<<<BS_ * 64 / 256, 256, 0, stream>>>(
        PCS_bf, parent, attn_bf);

    // GEMM2: out(fp32) = attn @ Wo + bo
    // 64x64 tile, BK=64 -> 8x64 = 512 blocks = 2.0 blocks/CU
    gemm_mfma_kernel<64, 64, 64, false>
        <<<dim3(E_ / 64, BS_ / 64), 256, 0, stream>>>(
        attn_bf, Wo_t, bo, bo, bo, out, E_, K_);
}

// Round 13
// 113.429 us; speedup vs baseline: 2.8359x; 1.0278x over previous
//
#include <hip/hip_runtime.h>
#include <hip/hip_bf16.h>

// Problem constants
#define B_  2
#define S_  2048
#define E_  512
#define H_  8
#define D_  64
#define BS_ (B_ * S_)   // 4096 rows
#define N1_ 1536        // fused tri-projection output cols
#define K_  512

typedef __bf16 bf16x8 __attribute__((ext_vector_type(8)));
typedef float  f32x4  __attribute__((ext_vector_type(4)));
typedef unsigned short us8 __attribute__((ext_vector_type(8)));

// float -> bf16 (RNE) bit trick
__device__ __forceinline__ ushort f2bf(float f) {
    unsigned u = __float_as_uint(f);
    unsigned r = (u + 0x7FFFu + ((u >> 16) & 1u)) >> 16;
    return (ushort)r;
}
__device__ __forceinline__ float bf2f(ushort b) {
    return __uint_as_float(((unsigned)b) << 16);
}

// async global->LDS, 16 B per lane; LDS dest = wave-uniform base + lane*16
__device__ __forceinline__ void gld_lds16(const ushort* g, ushort* l) {
    __builtin_amdgcn_global_load_lds(
        (const __attribute__((address_space(1))) unsigned int*)g,
        (__attribute__((address_space(3))) unsigned int*)l, 16, 0, 0);
}

// ---------------- merged prep kernel ----------------
// blocks [0,2048): fp32->bf16 convert of x (one float4 per thread)
// blocks [2048,2304): 64x64 transpose tiles of the four 512x512 weights
__global__ __launch_bounds__(256) void prep_kernel(
    const float* __restrict__ x, ushort* __restrict__ xb,
    const float* __restrict__ Wp, const float* __restrict__ Wc,
    const float* __restrict__ Ws, const float* __restrict__ Wo,
    ushort* __restrict__ Wcat_t, ushort* __restrict__ Wo_t) {
    int bid = blockIdx.x;
    int tid = threadIdx.x;
    if (bid < 2048) {
        int i = bid * 256 + tid;          // 524288 float4s total
        float4 v = ((const float4*)x)[i];
        ushort4 o;
        o.x = f2bf(v.x); o.y = f2bf(v.y); o.z = f2bf(v.z); o.w = f2bf(v.w);
        ((ushort4*)xb)[i] = o;
        return;
    }
    __shared__ ushort T[64][65];
    int bid2 = bid - 2048;                // 0..255
    int z = bid2 >> 6;
    int t = bid2 & 63;
    const float* src = (z == 0) ? Wp : (z == 1) ? Wc : (z == 2) ? Ws : Wo;
    ushort* dst = (z < 3) ? (Wcat_t + (size_t)z * 512 * 512) : Wo_t;
    int n0 = (t & 7) * 64, k0 = (t >> 3) * 64;
    int g = tid >> 6, l = tid & 63;
    #pragma unroll
    for (int r = 0; r < 16; r++) {
        int kk = g * 16 + r;
        T[kk][l] = f2bf(src[(size_t)(k0 + kk) * 512 + n0 + l]);  // coalesced read
    }
    __syncthreads();
    #pragma unroll
    for (int r = 0; r < 16; r++) {
        int nn = g * 16 + r;
        dst[(size_t)(n0 + nn) * 512 + k0 + l] = T[l][nn];        // coalesced write
    }
}

// ---------------- bf16 MFMA GEMM (m97 structure, tile-templated) ----------------
// C[M x N] = A[M x K](bf16) * Bt[N x K](bf16)^T + bias; output fp32 or bf16.
// 256 threads = 4 waves in 2x2; per-wave FM x NF fragments of 16x16x32.
// BK=64 (BK=128 measured -1.9us, round-12; coop grid.sync ~60us, round-11).
template<int TM, int TN, bool BF16OUT>
__global__ __launch_bounds__(256) void gemm_mfma_kernel(
    const ushort* __restrict__ A,   // M x K
    const ushort* __restrict__ Bt,  // N x K
    const float*  __restrict__ b0,  // bias cols [0,512)
    const float*  __restrict__ b1,  // bias cols [512,1024)
    const float*  __restrict__ b2,  // bias cols [1024,1536)
    void* __restrict__ Cv,          // M x N
    int N, int K) {
    constexpr int TK = 64;
    constexpr int FM = TM / 32;          // m-frags per wave
    constexpr int NF = TN / 32;          // n-frags per wave
    __shared__ ushort As[TM][TK];        // no pad (global_load_lds layout)
    __shared__ ushort Bs[TN][TK];

    const int tid  = threadIdx.x;
    const int lane = tid & 63;
    const int wave = tid >> 6;
    const int wm = wave >> 1, wn = wave & 1;
    const int row0 = blockIdx.y * TM;
    const int col0 = blockIdx.x * TN;

    f32x4 acc[FM][NF] = {};

    const int srow = lane >> 3;          // 0..7 row within an 8-row issue
    const int scol = (lane & 7) * 8;     // 8-bf16 chunk

    const int lrow = lane & 15;
    const int lk   = (lane >> 4) * 8;

    for (int kt = 0; kt < K; kt += TK) {
        const ushort* ga = A + (size_t)(row0 + wave * (TM / 4) + srow) * K + kt + scol;
        #pragma unroll
        for (int j = 0; j < FM; j++)
            gld_lds16(ga + (size_t)j * 8 * K, &As[wave * (TM / 4) + j * 8][0]);
        const ushort* gb = Bt + (size_t)(col0 + wave * (TN / 4) + srow) * K + kt + scol;
        #pragma unroll
        for (int j = 0; j < NF; j++)
            gld_lds16(gb + (size_t)j * 8 * K, &Bs[wave * (TN / 4) + j * 8][0]);
        __syncthreads();

        #pragma unroll
        for (int kk = 0; kk < TK; kk += 32) {
            bf16x8 af[FM], bfr[NF];
            #pragma unroll
            for (int i = 0; i < FM; i++)
                af[i] = *(const bf16x8*)(&As[wm * (FM * 16) + i * 16 + lrow][kk + lk]);
            #pragma unroll
            for (int j = 0; j < NF; j++)
                bfr[j] = *(const bf16x8*)(&Bs[wn * (TN / 2) + j * 16 + lrow][kk + lk]);
            #pragma unroll
            for (int i = 0; i < FM; i++)
                #pragma unroll
                for (int j = 0; j < NF; j++)
                    acc[i][j] = __builtin_amdgcn_mfma_f32_16x16x32_bf16(
                        af[i], bfr[j], acc[i][j], 0, 0, 0);
        }
        __syncthreads();
    }

    // C/D layout: col = lane&15, row = (lane>>4)*4 + reg  [m89/m91 verified]
    const int ccol = lane & 15;
    const int crow = (lane >> 4) * 4;
    #pragma unroll
    for (int j = 0; j < NF; j++) {
        int gcol = col0 + wn * (TN / 2) + j * 16 + ccol;
        float bias = (gcol < 512) ? b0[gcol]
                   : (gcol < 1024) ? b1[gcol - 512] : b2[gcol - 1024];
        #pragma unroll
        for (int i = 0; i < FM; i++) {
            int grow = row0 + wm * (FM * 16) + i * 16 + crow;
            #pragma unroll
            for (int rg = 0; rg < 4; rg++) {
                float v = acc[i][j][rg] + bias;
                if (BF16OUT)
                    ((ushort*)Cv)[(size_t)(grow + rg) * N + gcol] = f2bf(v);
                else
                    ((float*)Cv)[(size_t)(grow + rg) * N + gcol] = v;
            }
        }
    }
}

// ---------------- tree attention: 16B/lane ballot-scan gather ----------------
// PCS (bf16) row layout per token w (1536): [p(512)|c(512)|s(512)], each h*64+d.
// One wave per row n. Lane L owns 8 consecutive elements at offset L*8 of each
// 512-segment: head h = L>>3. Per edge: two dwordx4 loads, 8-FMA dot partial,
// shfl_xor(1,2,4) reduce within the 8-lane head group, one exp, 8 FMAs.
// Neighbor set {parent[n]} ∪ {m:parent[m]==n} minus duplicates, processed in
// fixed order -> bit-deterministic. No atomics.
// NOTE: alpha is PER-HEAD — the s@Wo pre-fold is invalid (round-7 post-mortem).
__global__ __launch_bounds__(256) void attn_gather_kernel(
    const ushort* __restrict__ PCS, const int* __restrict__ parent,
    ushort* __restrict__ attn) {
    int gtid = blockIdx.x * blockDim.x + threadIdx.x;
    int w    = gtid >> 6;        // token row 0..BS_-1
    int lane = gtid & 63;
    int bbase = ((w >> 11) << 11);
    int i  = w & (S_ - 1);
    int rp = bbase + parent[w];

    // p fragment: 8 consecutive bf16 at w*1536 + lane*8
    float pnf[8];
    {
        us8 p8 = *(const us8*)(PCS + (size_t)w * N1_ + lane * 8);
        #pragma unroll
        for (int j = 0; j < 8; j++) pnf[j] = bf2f(p8[j]);
    }

    float Z, av[8];
    // parent edge (always present in the mask)
    {
        const ushort* rm = PCS + (size_t)rp * N1_;
        us8 c8 = *(const us8*)(rm + 512  + lane * 8);
        us8 s8 = *(const us8*)(rm + 1024 + lane * 8);
        float t = 0.f;
        #pragma unroll
        for (int j = 0; j < 8; j++) t += pnf[j] * bf2f(c8[j]);
        t += __shfl_xor(t, 1); t += __shfl_xor(t, 2); t += __shfl_xor(t, 4);
        float e = __expf(t * 0.125f);          // 1/sqrt(D) = 1/8
        Z = e;
        #pragma unroll
        for (int j = 0; j < 8; j++) av[j] = e * bf2f(s8[j]);
    }

    // children: scan this batch's parent slice, 256 ints per step (int4/lane)
    for (int t0 = 0; t0 < S_; t0 += 256) {
        int4 pv = *(const int4*)(parent + bbase + t0 + lane * 4);
        int pc[4] = {pv.x, pv.y, pv.z, pv.w};
        #pragma unroll
        for (int jj = 0; jj < 4; jj++) {
            unsigned long long mask = __ballot(pc[jj] == i);
            while (mask) {
                int l = __ffsll(mask) - 1;
                mask &= mask - 1;
                int c = bbase + t0 + l * 4 + jj;
                if (c == rp) continue;         // mutual/self edge counted once
                const ushort* rc = PCS + (size_t)c * N1_;
                us8 c8 = *(const us8*)(rc + 512  + lane * 8);
                us8 s8 = *(const us8*)(rc + 1024 + lane * 8);
                float t = 0.f;
                #pragma unroll
                for (int j = 0; j < 8; j++) t += pnf[j] * bf2f(c8[j]);
                t += __shfl_xor(t, 1); t += __shfl_xor(t, 2); t += __shfl_xor(t, 4);
                float e = __expf(t * 0.125f);
                Z += e;
                #pragma unroll
                for (int j = 0; j < 8; j++) av[j] += e * bf2f(s8[j]);
            }
        }
    }

    float rz = 1.0f / Z;
    us8 o8;
    #pragma unroll
    for (int j = 0; j < 8; j++) o8[j] = f2bf(av[j] * rz);
    *(us8*)(attn + (size_t)w * E_ + lane * 8) = o8;
}

// ---------------- launch ----------------
extern "C" void kernel_launch(void* const* d_in, const int* in_sizes, int n_in,
                              void* d_out, int out_size, void* d_ws, size_t ws_size,
                              hipStream_t stream) {
    const float* x      = (const float*)d_in[0];
    const int*   parent = (const int*)  d_in[1];
    const float* Wp     = (const float*)d_in[2];
    const float* bp     = (const float*)d_in[3];
    const float* Wc     = (const float*)d_in[4];
    const float* bc     = (const float*)d_in[5];
    const float* Ws     = (const float*)d_in[6];
    const float* bs     = (const float*)d_in[7];
    const float* Wo     = (const float*)d_in[8];
    const float* bo     = (const float*)d_in[9];
    float* out = (float*)d_out;

    char* ws = (char*)d_ws;
    // workspace layout (bytes, 256-aligned); every byte read is written first
    ushort* x_bf    = (ushort*)(ws + 0);          //  4,194,304
    ushort* Wcat_t  = (ushort*)(ws + 4194304);    //  1,572,864
    ushort* Wo_t    = (ushort*)(ws + 5767168);    //    524,288
    ushort* PCS_bf  = (ushort*)(ws + 6291456);    // 12,582,912
    ushort* attn_bf = (ushort*)(ws + 18874368);   //  4,194,304  (end ~23.1 MB)

    // prep: convert x (2048 blocks) + transpose weights (256 blocks)
    prep_kernel<<<2304, 256, 0, stream>>>(x, x_bf, Wp, Wc, Ws, Wo, Wcat_t, Wo_t);

    // GEMM1: PCS(bf16) = x @ [Wp|Wc|Ws] + [bp|bc|bs]
    // 128x96 tile -> 16x32 = 512 blocks = exactly 2.0 blocks/CU
    gemm_mfma_kernel<128, 96, true>
        <<<dim3(N1_ / 96, BS_ / 128), 256, 0, stream>>>(
        x_bf, Wcat_t, bp, bc, bs, PCS_bf, N1_, K_);

    // tree attention: deterministic gather, 16B/lane loads, no atomics
    attn_gather_kernel<<<BS_ * 64 / 256, 256, 0, stream>>>(
        PCS_bf, parent, attn_bf);

    // GEMM2: out(fp32) = attn @ Wo + bo
    // 64x64 tile -> 8x64 = 512 blocks = 2.0 blocks/CU
    gemm_mfma_kernel<64, 64, false>
        <<<dim3(E_ / 64, BS_ / 64), 256, 0, stream>>>(
        attn_bf, Wo_t, bo, bo, bo, out, E_, K_);
}